// Round 8
// baseline (470.784 us; speedup 1.0000x reference)
//
#include <hip/hip_runtime.h>
#include <hip/hip_bf16.h>

// Flow_6081673691683: Heun flow (10 steps x 2 MLP evals, H=256) + analytic logdet.
// logabsdet = 240*ln(0.95) exactly -> jacrev/slogdet eliminated.
// R8: occupancy experiment. M=4 samples/block, 512 blocks -> 2 blocks/CU
// (__launch_bounds__(512,4)). Per-block path identical to R7 (3-barrier eval,
// redundant full-K L4, intra-wave transpose); co-resident blocks fill each
// other's barrier/latency stalls. Pad rows 4..15 compute bounded garbage.

typedef unsigned short ushort_t;
typedef float f32x4 __attribute__((ext_vector_type(4)));
typedef short s16x8 __attribute__((ext_vector_type(8)));

#define NB      2048
#define OBS_D   48
#define XDIM    24
#define NSTEPS  10
#define DT      0.1f
#define PP      0.95f
#define SCL     2.885390081777927f   // 2*log2(e)
#define MROWS   4                    // real samples per block

// d_ws layout (ushort / bf16 elements)
#define W1U  0        // full W1 frags (init cinit only): 16384
#define W2U  16384    // 65536
#define W3U  81920    // 65536
#define W4U  147456   // 4096 (unscaled, all 8 kt)
#define W1AU 151552   // act-only W1 frags (k<12) + t-row (k==16): 8192
#define FRAG_BLOCKS 624   // 624*256 == 159744
#define LP_BLOCKS 8

// LDS layout (bytes)
#define LDS_B0   0        // 8192  h1 (16 rows x 512B, packed pairs, XOR (r&7)<<4)
#define LDS_B1   8192     // 8192  h2
#define LDS_B2   16384    // 8192  h3
#define LDS_SCR  24576    // 10240 (8 waves x 16 rows x 80B transpose scratch)
#define LDS_STG  34816    // 2048  (init staging: 16 rows x 128B)
#define LDS_TOTAL 36864

__device__ __forceinline__ ushort_t f2bf(float f) {
  unsigned u = __builtin_bit_cast(unsigned, f);
  u += 0x7fffu + ((u >> 16) & 1u);          // RNE
  return (ushort_t)(u >> 16);
}

// input pre-scaled by 2*log2(e):  tanh = 1 - 2/(1 + exp2(u))
__device__ __forceinline__ float tanh_s(float u) {
  float e = __builtin_amdgcn_exp2f(u);
  return __builtin_fmaf(-2.f, __builtin_amdgcn_rcpf(1.f + e), 1.f);
}

// packed-pair byte offset within a 128B row (cols 0..63), pre-swizzle
__device__ __forceinline__ int pair_byte(int c) {
  return (((c >> 5) << 6) | ((c & 15) << 2) | (((c >> 4) & 1) << 1));
}

// ---------------------------------------------------------------------------
// Prep: weights -> bf16 MFMA B-fragment order (permuted K) + analytic log_probs.
// k_eff = kt*32 + 4*(l>>4) + (j>>1) + 16*(j&1). W1/W2/W3 scaled by 2*log2(e).
// W1A carries act rows (k<12) and W1's t-row (60) remapped to k==16.
// ---------------------------------------------------------------------------
__global__ void prep_kernel(const float* __restrict__ W1, const float* __restrict__ b1,
                            const float* __restrict__ W2, const float* __restrict__ W3,
                            const float* __restrict__ W4, const float* __restrict__ x0,
                            const int* __restrict__ jac, float* __restrict__ out,
                            ushort_t* __restrict__ ws) {
  int bid = blockIdx.x;
  int tid = threadIdx.x;
  if (bid < FRAG_BLOCKS) {
    int e = bid * 256 + tid;           // 0 .. 159743
    float val = 0.f;
    if (e < 16384) {                   // W1 full (61x256 + b1 row 61), scaled
      int kt = e >> 13; int r = e & 8191;
      int nt = r >> 9, l = (r >> 3) & 63, j = r & 7;
      int k = kt * 32 + ((l >> 4) << 2) + (j >> 1) + ((j & 1) << 4);
      int col = nt * 16 + (l & 15);
      val = SCL * ((k < 61) ? W1[k * 256 + col] : ((k == 61) ? b1[col] : 0.f));
    } else if (e < 81920) {            // W2, scaled
      int e2 = e - 16384;
      int kt = e2 >> 13; int r = e2 & 8191;
      int nt = r >> 9, l = (r >> 3) & 63, j = r & 7;
      int k = kt * 32 + ((l >> 4) << 2) + (j >> 1) + ((j & 1) << 4);
      val = SCL * W2[k * 256 + nt * 16 + (l & 15)];
    } else if (e < 147456) {           // W3, scaled
      int e2 = e - 81920;
      int kt = e2 >> 13; int r = e2 & 8191;
      int nt = r >> 9, l = (r >> 3) & 63, j = r & 7;
      int k = kt * 32 + ((l >> 4) << 2) + (j >> 1) + ((j & 1) << 4);
      val = SCL * W3[k * 256 + nt * 16 + (l & 15)];
    } else if (e < 151552) {           // W4 (256x12 -> N pad 16), UNscaled
      int e2 = e - 147456;
      int kt = e2 >> 9; int r = e2 & 511;
      int l = (r >> 3) & 63, j = r & 7;
      int k = kt * 32 + ((l >> 4) << 2) + (j >> 1) + ((j & 1) << 4);
      int col = l & 15;
      val = (col < 12) ? W4[k * 12 + col] : 0.f;
    } else {                           // W1A: act rows (k<12) + t-row at k==16
      int e2 = e - 151552;
      int nt = e2 >> 9; int r = e2 & 511;
      int l = (r >> 3) & 63, j = r & 7;
      int k = ((l >> 4) << 2) + (j >> 1) + ((j & 1) << 4);
      int col = nt * 16 + (l & 15);
      val = (k < 12) ? SCL * W1[k * 256 + col]
          : ((k == 16) ? SCL * W1[60 * 256 + col] : 0.f);
    }
    ws[e] = f2bf(val);
  } else {
    int s = (bid - FRAG_BLOCKS) * 256 + tid;   // 0..2047
    float acc = 0.f;
    #pragma unroll 4
    for (int j = 0; j < XDIM; ++j) { float v = x0[s * XDIM + j]; acc += v * v; }
    // -0.5*d*ln(2pi) = -22.054524796912143 ; -240*ln(0.95) = +12.310390653012128
    float C = (jac[0] != 0) ? -9.744134143900015f : -22.054524796912143f;
    out[NB * XDIM + s] = -0.5f * acc + C;
  }
}

// ---------------------------------------------------------------------------
// Main: 512 blocks x 512 threads (8 waves), 4 real samples/block (rows 0..3),
// rows 4..15 pad. 2 blocks/CU via __launch_bounds__(512,4).
// ---------------------------------------------------------------------------
__global__ __launch_bounds__(512, 4) void flow_main(
    const float* __restrict__ obs, const float* __restrict__ x0,
    const float* __restrict__ b2g, const float* __restrict__ b3g,
    const float* __restrict__ b4g, const ushort_t* __restrict__ ws,
    float* __restrict__ out) {
  __shared__ char lds[LDS_TOTAL];
  const int tid  = threadIdx.x;
  const int lane = tid & 63;
  const int wv   = tid >> 6;
  const int g    = lane >> 4;
  const int ar   = lane & 15;
  const int row0 = blockIdx.x * MROWS;
  const int sw   = (ar & 7) << 4;

  // precomputed LDS offsets
  int roff[8], woff[4], swoff[4];
  #pragma unroll
  for (int kt = 0; kt < 8; ++kt) roff[kt] = ar * 512 + ((kt * 64 + g * 16) ^ sw);
  #pragma unroll
  for (int r = 0; r < 4; ++r) {
    int rw = 4 * g + r;
    woff[r]  = rw * 512 + ((wv * 64 + ar * 4) ^ ((rw & 7) << 4));
    swoff[r] = LDS_SCR + wv * 1280 + rw * 80 + ar * 4;
  }
  const int sroff = LDS_SCR + wv * 1280 + ar * 80 + g * 16;

  // --- init staging: [0(act)|obs|0(t)|1(bias)]; rows >= MROWS stay zero ---
  ((unsigned*)(lds + LDS_STG))[tid] = 0u;    // 512 dwords = 2048 B
  __syncthreads();
  if (tid < MROWS * OBS_D) {
    int r = tid / OBS_D, o = tid - r * OBS_D;
    int byt = pair_byte(12 + o) ^ ((r & 7) << 4);
    *(ushort_t*)(lds + LDS_STG + r * 128 + byt) = f2bf(obs[(row0 + r) * OBS_D + o]);
  }
  if (tid < 16)
    *(ushort_t*)(lds + LDS_STG + tid * 128 + (pair_byte(61) ^ ((tid & 7) << 4))) = (ushort_t)0x3F80;

  // --- Heun state (per-lane, redundant in all waves): rows 4g+r, col ar ---
  // only g==0 rows are real samples
  float zst[4], yst[4], zin[4];
  #pragma unroll
  for (int r = 0; r < 4; ++r) {
    zst[r] = (g == 0 && ar < 12) ? x0[(row0 + r) * XDIM + ar] : 0.f;
    yst[r] = (g == 0 && ar < 12) ? x0[(row0 + r) * XDIM + 12 + ar] : 0.f;
    zin[r] = 0.f;
  }

  // --- initial act fragment from y0 (t=0); pad rows (ar>=MROWS) zero ---
  union FU { s16x8 v; unsigned u[4]; };
  FU af;
  {
    f32x4 av = {0.f, 0.f, 0.f, 0.f};
    if (g < 3 && ar < MROWS) av = *(const f32x4*)(x0 + (row0 + ar) * XDIM + 12 + 4 * g);
    const float zf = 0.f;
    asm("v_cvt_pk_bf16_f32 %0, %1, %2" : "=v"(af.u[0]) : "v"(av[0]), "v"(zf));
    asm("v_cvt_pk_bf16_f32 %0, %1, %2" : "=v"(af.u[1]) : "v"(av[1]), "v"(zf));
    asm("v_cvt_pk_bf16_f32 %0, %1, %2" : "=v"(af.u[2]) : "v"(av[2]), "v"(zf));
    asm("v_cvt_pk_bf16_f32 %0, %1, %2" : "=v"(af.u[3]) : "v"(av[3]), "v"(zf));
  }

  // --- weight fragments (pinned) ---
  s16x8 w1o[2][2], w1a[2], w2r[8][2], w3r[8][2], w4F[8];
  #pragma unroll
  for (int kt = 0; kt < 2; ++kt)
    #pragma unroll
    for (int n = 0; n < 2; ++n)
      w1o[kt][n] = *(const s16x8*)(ws + W1U + (((kt * 16) + (2 * wv + n)) * 64 + lane) * 8);
  #pragma unroll
  for (int n = 0; n < 2; ++n)
    w1a[n] = *(const s16x8*)(ws + W1AU + ((2 * wv + n) * 64 + lane) * 8);
  #pragma unroll
  for (int kt = 0; kt < 8; ++kt) {
    #pragma unroll
    for (int n = 0; n < 2; ++n) {
      w2r[kt][n] = *(const s16x8*)(ws + W2U + (((kt * 16) + (2 * wv + n)) * 64 + lane) * 8);
      w3r[kt][n] = *(const s16x8*)(ws + W3U + (((kt * 16) + (2 * wv + n)) * 64 + lane) * 8);
    }
    w4F[kt] = *(const s16x8*)(ws + W4U + (kt * 64 + lane) * 8);
  }
  asm volatile("" : "+v"(w1a[0]), "+v"(w1a[1]));
  #pragma unroll
  for (int kt = 0; kt < 8; ++kt)
    asm volatile("" : "+v"(w2r[kt][0]), "+v"(w2r[kt][1]), "+v"(w3r[kt][0]),
                     "+v"(w3r[kt][1]), "+v"(w4F[kt]));

  const float b2s0 = SCL * b2g[32 * wv + ar],  b2s1 = SCL * b2g[32 * wv + 16 + ar];
  const float b3s0 = SCL * b3g[32 * wv + ar],  b3s1 = SCL * b3g[32 * wv + 16 + ar];
  const float b4s  = (ar < 12) ? b4g[ar] : 0.f;

  __syncthreads();

  // --- cinit = ([0|obs|0|1] @ W1s): step-invariant L1 pre-activation ---
  const f32x4 z4 = {0.f, 0.f, 0.f, 0.f};
  f32x4 ci0 = z4, ci1 = z4;
  #pragma unroll
  for (int kt = 0; kt < 2; ++kt) {
    s16x8 a = *(const s16x8*)(lds + LDS_STG + ar * 128 + ((kt * 64 + g * 16) ^ sw));
    ci0 = __builtin_amdgcn_mfma_f32_16x16x32_bf16(a, w1o[kt][0], ci0, 0, 0, 0);
    ci1 = __builtin_amdgcn_mfma_f32_16x16x32_bf16(a, w1o[kt][1], ci1, 0, 0, 0);
  }
  // (STG never reused -> no extra barrier; first L1 write is B0)

  // ---- one MLP eval: af -> p4 (L4 out rows 4g+r, col ar; b4 in C-init) ----
  auto EVAL = [&](f32x4& p4) {
    // L1
    f32x4 acc0 = ci0, acc1 = ci1;
    acc0 = __builtin_amdgcn_mfma_f32_16x16x32_bf16(af.v, w1a[0], acc0, 0, 0, 0);
    acc1 = __builtin_amdgcn_mfma_f32_16x16x32_bf16(af.v, w1a[1], acc1, 0, 0, 0);
    #pragma unroll
    for (int r = 0; r < 4; ++r) {
      unsigned p;
      float lo = tanh_s(acc0[r]), hi = tanh_s(acc1[r]);
      asm("v_cvt_pk_bf16_f32 %0, %1, %2" : "=v"(p) : "v"(lo), "v"(hi));
      *(unsigned*)(lds + LDS_B0 + woff[r]) = p;
    }
    __syncthreads();
    // L2
    f32x4 a0a = {b2s0, b2s0, b2s0, b2s0}, a1a = {b2s1, b2s1, b2s1, b2s1};
    f32x4 a0b = z4, a1b = z4;
    #pragma unroll
    for (int kt = 0; kt < 4; ++kt) {
      s16x8 a = *(const s16x8*)(lds + LDS_B0 + roff[kt]);
      s16x8 b = *(const s16x8*)(lds + LDS_B0 + roff[kt + 4]);
      a0a = __builtin_amdgcn_mfma_f32_16x16x32_bf16(a, w2r[kt][0], a0a, 0, 0, 0);
      a1a = __builtin_amdgcn_mfma_f32_16x16x32_bf16(a, w2r[kt][1], a1a, 0, 0, 0);
      a0b = __builtin_amdgcn_mfma_f32_16x16x32_bf16(b, w2r[kt + 4][0], a0b, 0, 0, 0);
      a1b = __builtin_amdgcn_mfma_f32_16x16x32_bf16(b, w2r[kt + 4][1], a1b, 0, 0, 0);
    }
    acc0 = a0a + a0b; acc1 = a1a + a1b;
    #pragma unroll
    for (int r = 0; r < 4; ++r) {
      unsigned p;
      float lo = tanh_s(acc0[r]), hi = tanh_s(acc1[r]);
      asm("v_cvt_pk_bf16_f32 %0, %1, %2" : "=v"(p) : "v"(lo), "v"(hi));
      *(unsigned*)(lds + LDS_B1 + woff[r]) = p;
    }
    __syncthreads();
    // L3
    a0a = (f32x4){b3s0, b3s0, b3s0, b3s0}; a1a = (f32x4){b3s1, b3s1, b3s1, b3s1};
    a0b = z4; a1b = z4;
    #pragma unroll
    for (int kt = 0; kt < 4; ++kt) {
      s16x8 a = *(const s16x8*)(lds + LDS_B1 + roff[kt]);
      s16x8 b = *(const s16x8*)(lds + LDS_B1 + roff[kt + 4]);
      a0a = __builtin_amdgcn_mfma_f32_16x16x32_bf16(a, w3r[kt][0], a0a, 0, 0, 0);
      a1a = __builtin_amdgcn_mfma_f32_16x16x32_bf16(a, w3r[kt][1], a1a, 0, 0, 0);
      a0b = __builtin_amdgcn_mfma_f32_16x16x32_bf16(b, w3r[kt + 4][0], a0b, 0, 0, 0);
      a1b = __builtin_amdgcn_mfma_f32_16x16x32_bf16(b, w3r[kt + 4][1], a1b, 0, 0, 0);
    }
    acc0 = a0a + a0b; acc1 = a1a + a1b;
    #pragma unroll
    for (int r = 0; r < 4; ++r) {
      unsigned p;
      float lo = tanh_s(acc0[r]), hi = tanh_s(acc1[r]);
      asm("v_cvt_pk_bf16_f32 %0, %1, %2" : "=v"(p) : "v"(lo), "v"(hi));
      *(unsigned*)(lds + LDS_B2 + woff[r]) = p;
    }
    __syncthreads();
    // L4: full K=256, every wave redundantly (8 MFMA, 2 chains, b4 C-init)
    f32x4 pa = {b4s, b4s, b4s, b4s}, pb = z4;
    #pragma unroll
    for (int kt = 0; kt < 4; ++kt) {
      s16x8 a = *(const s16x8*)(lds + LDS_B2 + roff[kt]);
      s16x8 b = *(const s16x8*)(lds + LDS_B2 + roff[kt + 4]);
      pa = __builtin_amdgcn_mfma_f32_16x16x32_bf16(a, w4F[kt], pa, 0, 0, 0);
      pb = __builtin_amdgcn_mfma_f32_16x16x32_bf16(b, w4F[kt + 4], pb, 0, 0, 0);
    }
    p4 = pa + pb;
  };

  // ---- intra-wave transpose: C-layout val -> next L1 A-frag (NO s_barrier) ----
  auto TRANSPOSE = [&](const float* val, float tnext) {
    #pragma unroll
    for (int r = 0; r < 4; ++r)
      *(float*)(lds + swoff[r]) = (ar < 12) ? val[r] : 0.f;
    asm volatile("s_waitcnt lgkmcnt(0)" ::: "memory");
    __builtin_amdgcn_sched_barrier(0);
    f32x4 a4 = *(const f32x4*)(lds + sroff);
    float hi0 = (g == 0) ? tnext : 0.f;
    const float zf = 0.f;
    asm("v_cvt_pk_bf16_f32 %0, %1, %2" : "=v"(af.u[0]) : "v"(a4[0]), "v"(hi0));
    asm("v_cvt_pk_bf16_f32 %0, %1, %2" : "=v"(af.u[1]) : "v"(a4[1]), "v"(zf));
    asm("v_cvt_pk_bf16_f32 %0, %1, %2" : "=v"(af.u[2]) : "v"(a4[2]), "v"(zf));
    asm("v_cvt_pk_bf16_f32 %0, %1, %2" : "=v"(af.u[3]) : "v"(a4[3]), "v"(zf));
  };

  for (int i = 0; i < NSTEPS; ++i) {
    f32x4 p4;
    // ev0: input y (af), t = i*DT (folded in af)
    EVAL(p4);
    #pragma unroll
    for (int r = 0; r < 4; ++r) zin[r] = __builtin_fmaf(DT, p4[r], zst[r]);
    TRANSPOSE(zin, (float)i * DT);
    // ev1: input z_in
    EVAL(p4);
    #pragma unroll
    for (int r = 0; r < 4; ++r) {
      float yi = __builtin_fmaf(DT, p4[r], yst[r]);
      zst[r] = PP * zin[r] + (1.f - PP) * yi;
      yst[r] = PP * yi + (1.f - PP) * zst[r];
    }
    TRANSPOSE(yst, (float)(i + 1) * DT);
  }

  // ---- output (wave 0, g==0 rows = the 4 real samples) ----
  if (wv == 0 && g == 0 && ar < 12) {
    #pragma unroll
    for (int r = 0; r < 4; ++r) {
      out[(row0 + r) * XDIM + ar]      = zst[r];
      out[(row0 + r) * XDIM + 12 + ar] = yst[r];
    }
  }
}

extern "C" void kernel_launch(void* const* d_in, const int* in_sizes, int n_in,
                              void* d_out, int out_size, void* d_ws, size_t ws_size,
                              hipStream_t stream) {
  const float* obs = (const float*)d_in[0];
  const float* x0  = (const float*)d_in[1];
  const float* W1  = (const float*)d_in[2];
  const float* b1  = (const float*)d_in[3];
  const float* W2  = (const float*)d_in[4];
  const float* b2  = (const float*)d_in[5];
  const float* W3  = (const float*)d_in[6];
  const float* b3  = (const float*)d_in[7];
  const float* W4  = (const float*)d_in[8];
  const float* b4  = (const float*)d_in[9];
  const int*   jac = (const int*)d_in[10];
  float* out = (float*)d_out;
  ushort_t* ws = (ushort_t*)d_ws;

  prep_kernel<<<FRAG_BLOCKS + LP_BLOCKS, 256, 0, stream>>>(W1, b1, W2, W3, W4, x0, jac, out, ws);
  flow_main<<<NB / MROWS, 512, 0, stream>>>(obs, x0, b2, b3, b4, ws, out);
}

// Round 9
// 47.197 us; speedup vs baseline: 9.9748x; 9.9748x over previous
//
#include <hip/hip_runtime.h>
#include <hip/hip_bf16.h>

// Flow_6081673691683: Heun flow (10 steps x 2 MLP evals, H=256) + analytic logdet.
// logabsdet = 240*ln(0.95) exactly -> jacrev/slogdet eliminated.
// R9 = R6 (best, 46us) + stall-spreaders:
//  - kt-stagger per wave (rotation baked into load addrs + frag regs at init)
//  - 4x2 MFMA chains (was 2x4) to halve dep-chain latency
//  - s_setprio(1) around L2/L3 MFMA clusters
//  - PART write slot XOR (g<<1): 16-way -> 4-way bank conflict
// R8 lesson: launch_bounds(512,4) caps VGPR at 128 -> massive spill (470us).
// This kernel NEEDS ~200 regs -> 2 waves/SIMD is the occupancy ceiling.

typedef unsigned short ushort_t;
typedef float f32x4 __attribute__((ext_vector_type(4)));
typedef short s16x8 __attribute__((ext_vector_type(8)));

#define NB      2048
#define OBS_D   48
#define XDIM    24
#define NSTEPS  10
#define DT      0.1f
#define PP      0.95f
#define SCL     2.885390081777927f   // 2*log2(e)

// d_ws layout (ushort / bf16 elements)
#define W1U  0        // full W1 frags (init cinit only): 16384
#define W2U  16384    // 65536
#define W3U  81920    // 65536
#define W4U  147456   // 4096 (unscaled)
#define W1AU 151552   // act-only W1 frags (k<12, K=32): 8192
#define FRAG_BLOCKS 624   // 624*256 == 159744
#define LP_BLOCKS 8

// LDS layout (bytes)
#define LDS_BUFA 0        // 8192 (h1/h3: 16 rows x 512B, XOR (r&7)<<4)
#define LDS_BUFB 8192     // 8192 (h2; also init staging 16 x 128B)
#define LDS_AIN  16384    // 1024 (16 rows x 64B act-only, XOR (r&3)<<4)
#define LDS_PART 17408    // 8192 (16 row x 16 col x 8 slot f32; slot = wv^(g<<1))
#define LDS_TOTAL 25600

__device__ __forceinline__ ushort_t f2bf(float f) {
  unsigned u = __builtin_bit_cast(unsigned, f);
  u += 0x7fffu + ((u >> 16) & 1u);          // RNE
  return (ushort_t)(u >> 16);
}

// input pre-scaled by 2*log2(e):  tanh = 1 - 2/(1 + exp2(u))
__device__ __forceinline__ float tanh_s(float u) {
  float e = __builtin_amdgcn_exp2f(u);
  return __builtin_fmaf(-2.f, __builtin_amdgcn_rcpf(1.f + e), 1.f);
}

// packed-pair byte offset within a 128B row (cols 0..63), pre-swizzle
__device__ __forceinline__ int pair_byte(int c) {
  return (((c >> 5) << 6) | ((c & 15) << 2) | (((c >> 4) & 1) << 1));
}

// ---------------------------------------------------------------------------
// Prep: weights -> bf16 MFMA B-fragment order (permuted K) + analytic log_probs.
// k_eff = kt*32 + 4*(l>>4) + (j>>1) + 16*(j&1). W1/W2/W3 scaled by 2*log2(e).
// ---------------------------------------------------------------------------
__global__ void prep_kernel(const float* __restrict__ W1, const float* __restrict__ b1,
                            const float* __restrict__ W2, const float* __restrict__ W3,
                            const float* __restrict__ W4, const float* __restrict__ x0,
                            const int* __restrict__ jac, float* __restrict__ out,
                            ushort_t* __restrict__ ws) {
  int bid = blockIdx.x;
  int tid = threadIdx.x;
  if (bid < FRAG_BLOCKS) {
    int e = bid * 256 + tid;           // 0 .. 159743
    float val = 0.f;
    if (e < 16384) {                   // W1 full (61x256 + b1 row 61), scaled
      int kt = e >> 13; int r = e & 8191;
      int nt = r >> 9, l = (r >> 3) & 63, j = r & 7;
      int k = kt * 32 + ((l >> 4) << 2) + (j >> 1) + ((j & 1) << 4);
      int col = nt * 16 + (l & 15);
      val = SCL * ((k < 61) ? W1[k * 256 + col] : ((k == 61) ? b1[col] : 0.f));
    } else if (e < 81920) {            // W2, scaled
      int e2 = e - 16384;
      int kt = e2 >> 13; int r = e2 & 8191;
      int nt = r >> 9, l = (r >> 3) & 63, j = r & 7;
      int k = kt * 32 + ((l >> 4) << 2) + (j >> 1) + ((j & 1) << 4);
      val = SCL * W2[k * 256 + nt * 16 + (l & 15)];
    } else if (e < 147456) {           // W3, scaled
      int e2 = e - 81920;
      int kt = e2 >> 13; int r = e2 & 8191;
      int nt = r >> 9, l = (r >> 3) & 63, j = r & 7;
      int k = kt * 32 + ((l >> 4) << 2) + (j >> 1) + ((j & 1) << 4);
      val = SCL * W3[k * 256 + nt * 16 + (l & 15)];
    } else if (e < 151552) {           // W4 (256x12 -> N pad 16), UNscaled
      int e2 = e - 147456;
      int kt = e2 >> 9; int r = e2 & 511;
      int l = (r >> 3) & 63, j = r & 7;
      int k = kt * 32 + ((l >> 4) << 2) + (j >> 1) + ((j & 1) << 4);
      int col = l & 15;
      val = (col < 12) ? W4[k * 12 + col] : 0.f;
    } else {                           // W1A: act rows only (k<12), K=32, scaled
      int e2 = e - 151552;
      int nt = e2 >> 9; int r = e2 & 511;
      int l = (r >> 3) & 63, j = r & 7;
      int k = ((l >> 4) << 2) + (j >> 1) + ((j & 1) << 4);
      val = (k < 12) ? SCL * W1[k * 256 + nt * 16 + (l & 15)] : 0.f;
    }
    ws[e] = f2bf(val);
  } else {
    int s = (bid - FRAG_BLOCKS) * 256 + tid;   // 0..2047
    float acc = 0.f;
    #pragma unroll 4
    for (int j = 0; j < XDIM; ++j) { float v = x0[s * XDIM + j]; acc += v * v; }
    // -0.5*d*ln(2pi) = -22.054524796912143 ; -240*ln(0.95) = +12.310390653012128
    float C = (jac[0] != 0) ? -9.744134143900015f : -22.054524796912143f;
    out[NB * XDIM + s] = -0.5f * acc + C;
  }
}

// ---------------------------------------------------------------------------
// Main: 128 blocks x 512 threads (8 waves), 16 samples/block.
// ---------------------------------------------------------------------------
__global__ __launch_bounds__(512, 2) void flow_main(
    const float* __restrict__ obs, const float* __restrict__ x0,
    const float* __restrict__ W1g, const float* __restrict__ b2g,
    const float* __restrict__ b3g, const float* __restrict__ b4g,
    const ushort_t* __restrict__ ws, float* __restrict__ out) {
  __shared__ char lds[LDS_TOTAL];
  const int tid  = threadIdx.x;
  const int lane = tid & 63;
  const int wv   = tid >> 6;
  const int g    = lane >> 4;
  const int ar   = lane & 15;
  const int row0 = blockIdx.x * 16;
  const int sw   = (ar & 7) << 4;             // h-buffer read swizzle
  const int rs   = tid >> 4, cs = tid & 15;   // reduce role (tid<256)

  // staggered read offsets: roff[c] reads segment kt=(wv+c)&7
  int roff[8];
  #pragma unroll
  for (int c = 0; c < 8; ++c)
    roff[c] = ar * 512 + (((((wv + c) & 7) * 64) + g * 16) ^ sw);
  // h-write offsets (seg wv, row rw = 4g+r)
  int woff[4], pwoff[4];
  #pragma unroll
  for (int r = 0; r < 4; ++r) {
    int rw = 4 * g + r;
    woff[r]  = rw * 512 + ((wv * 64 + ar * 4) ^ ((rw & 7) << 4));
    pwoff[r] = LDS_PART + ((rw * 128 + ar * 8 + (wv ^ (g << 1))) << 2);
  }

  // --- zero STG (BUFB, 512 dw) and AIN (256 dw) ---
  ((unsigned*)(lds + LDS_BUFB))[tid] = 0u;
  if (tid < 256) ((unsigned*)(lds + LDS_AIN))[tid] = 0u;
  __syncthreads();

  // --- fill STG = [0(act)|obs|0(t)|1(bias)] for the cinit MFMA ---
  for (int idx = tid; idx < 16 * OBS_D; idx += 512) {
    int r = idx / OBS_D, o = idx - r * OBS_D;
    int byt = pair_byte(12 + o) ^ ((r & 7) << 4);
    *(ushort_t*)(lds + LDS_BUFB + r * 128 + byt) = f2bf(obs[(row0 + r) * OBS_D + o]);
  }
  if (tid < 16)   // col 61 = 1.0 -> b1 (scaled b1 lives in W1 frag row 61)
    *(ushort_t*)(lds + LDS_BUFB + tid * 128 + (pair_byte(61) ^ ((tid & 7) << 4))) = (ushort_t)0x3F80;

  // --- act seed (y0) into AIN + z/y state regs (tid<256 roles) ---
  float zr = 0.f, yr = 0.f, zir = 0.f;
  if (tid < 256 && cs < 12) {
    zr = x0[(row0 + rs) * XDIM + cs];
    yr = x0[(row0 + rs) * XDIM + 12 + cs];
    *(ushort_t*)(lds + LDS_AIN + rs * 64 + ((cs * 4) ^ ((rs & 3) << 4))) = f2bf(yr);
  }

  // --- weight fragments (STAGGERED: index c corresponds to kt=(wv+c)&7) ---
  s16x8 w1o[2][2], w1a[2], w2r[8][2], w3r[8][2], w4r;
  #pragma unroll
  for (int kt = 0; kt < 2; ++kt)
    #pragma unroll
    for (int n = 0; n < 2; ++n)
      w1o[kt][n] = *(const s16x8*)(ws + W1U + (((kt * 16) + (2 * wv + n)) * 64 + lane) * 8);
  #pragma unroll
  for (int n = 0; n < 2; ++n)
    w1a[n] = *(const s16x8*)(ws + W1AU + ((2 * wv + n) * 64 + lane) * 8);
  #pragma unroll
  for (int c = 0; c < 8; ++c) {
    int kt = (wv + c) & 7;
    #pragma unroll
    for (int n = 0; n < 2; ++n) {
      w2r[c][n] = *(const s16x8*)(ws + W2U + (((kt * 16) + (2 * wv + n)) * 64 + lane) * 8);
      w3r[c][n] = *(const s16x8*)(ws + W3U + (((kt * 16) + (2 * wv + n)) * 64 + lane) * 8);
    }
  }
  w4r = *(const s16x8*)(ws + W4U + (wv * 64 + lane) * 8);   // kt = wv (wave-local)
  asm volatile("" : "+v"(w1a[0]), "+v"(w1a[1]), "+v"(w4r));
  #pragma unroll
  for (int c = 0; c < 8; ++c)
    asm volatile("" : "+v"(w2r[c][0]), "+v"(w2r[c][1]), "+v"(w3r[c][0]), "+v"(w3r[c][1]));

  // t-row of W1 (scaled) + biases (scaled; folded into MFMA C-init)
  const float w1t0 = SCL * W1g[60 * 256 + 32 * wv + ar];
  const float w1t1 = SCL * W1g[60 * 256 + 32 * wv + 16 + ar];
  const float b2s0 = SCL * b2g[32 * wv + ar],      b2s1 = SCL * b2g[32 * wv + 16 + ar];
  const float b3s0 = SCL * b3g[32 * wv + ar],      b3s1 = SCL * b3g[32 * wv + 16 + ar];
  const float b4v  = (cs < 12) ? b4g[cs] : 0.f;

  __syncthreads();

  // --- cinit = ([0|obs|0|1] @ W1s): step-invariant L1 pre-activation ---
  const f32x4 z4 = {0.f, 0.f, 0.f, 0.f};
  f32x4 ci0 = z4, ci1 = z4;
  #pragma unroll
  for (int kt = 0; kt < 2; ++kt) {
    s16x8 a = *(const s16x8*)(lds + LDS_BUFB + ar * 128 + ((kt * 64 + g * 16) ^ sw));
    ci0 = __builtin_amdgcn_mfma_f32_16x16x32_bf16(a, w1o[kt][0], ci0, 0, 0, 0);
    ci1 = __builtin_amdgcn_mfma_f32_16x16x32_bf16(a, w1o[kt][1], ci1, 0, 0, 0);
  }
  // (STG never reused -> no extra barrier; first L1 write is BUFA)

  for (int i = 0; i < NSTEPS; ++i) {
    const float t = (float)i * DT;
    const float t0 = t * w1t0, t1 = t * w1t1;
    #pragma unroll
    for (int ev = 0; ev < 2; ++ev) {
      // ---- L1: act @ W1a + (cinit + t*w1t)  (1 read, 2 MFMA) ----
      f32x4 acc0 = ci0, acc1 = ci1;
      #pragma unroll
      for (int r = 0; r < 4; ++r) { acc0[r] += t0; acc1[r] += t1; }
      {
        s16x8 a = *(const s16x8*)(lds + LDS_AIN + ar * 64 + ((g * 16) ^ ((ar & 3) << 4)));
        acc0 = __builtin_amdgcn_mfma_f32_16x16x32_bf16(a, w1a[0], acc0, 0, 0, 0);
        acc1 = __builtin_amdgcn_mfma_f32_16x16x32_bf16(a, w1a[1], acc1, 0, 0, 0);
      }
      #pragma unroll
      for (int r = 0; r < 4; ++r) {
        unsigned p;
        float lo = tanh_s(acc0[r]), hi = tanh_s(acc1[r]);
        asm("v_cvt_pk_bf16_f32 %0, %1, %2" : "=v"(p) : "v"(lo), "v"(hi));
        *(unsigned*)(lds + LDS_BUFA + woff[r]) = p;
      }
      __syncthreads();

      // ---- L2: h1 @ W2 (staggered kt, 4x2-deep chains, bias in chain-0 init) ----
      f32x4 c0[4], c1[4];
      c0[0] = (f32x4){b2s0, b2s0, b2s0, b2s0}; c1[0] = (f32x4){b2s1, b2s1, b2s1, b2s1};
      c0[1] = z4; c0[2] = z4; c0[3] = z4; c1[1] = z4; c1[2] = z4; c1[3] = z4;
      __builtin_amdgcn_s_setprio(1);
      #pragma unroll
      for (int c = 0; c < 4; ++c) {
        s16x8 a = *(const s16x8*)(lds + LDS_BUFA + roff[c]);
        s16x8 b = *(const s16x8*)(lds + LDS_BUFA + roff[c + 4]);
        c0[c] = __builtin_amdgcn_mfma_f32_16x16x32_bf16(a, w2r[c][0], c0[c], 0, 0, 0);
        c1[c] = __builtin_amdgcn_mfma_f32_16x16x32_bf16(a, w2r[c][1], c1[c], 0, 0, 0);
        c0[c] = __builtin_amdgcn_mfma_f32_16x16x32_bf16(b, w2r[c + 4][0], c0[c], 0, 0, 0);
        c1[c] = __builtin_amdgcn_mfma_f32_16x16x32_bf16(b, w2r[c + 4][1], c1[c], 0, 0, 0);
      }
      __builtin_amdgcn_s_setprio(0);
      acc0 = (c0[0] + c0[1]) + (c0[2] + c0[3]);
      acc1 = (c1[0] + c1[1]) + (c1[2] + c1[3]);
      #pragma unroll
      for (int r = 0; r < 4; ++r) {
        unsigned p;
        float lo = tanh_s(acc0[r]), hi = tanh_s(acc1[r]);
        asm("v_cvt_pk_bf16_f32 %0, %1, %2" : "=v"(p) : "v"(lo), "v"(hi));
        *(unsigned*)(lds + LDS_BUFB + woff[r]) = p;
      }
      __syncthreads();

      // ---- L3: h2 @ W3 (same pattern) ----
      c0[0] = (f32x4){b3s0, b3s0, b3s0, b3s0}; c1[0] = (f32x4){b3s1, b3s1, b3s1, b3s1};
      c0[1] = z4; c0[2] = z4; c0[3] = z4; c1[1] = z4; c1[2] = z4; c1[3] = z4;
      __builtin_amdgcn_s_setprio(1);
      #pragma unroll
      for (int c = 0; c < 4; ++c) {
        s16x8 a = *(const s16x8*)(lds + LDS_BUFB + roff[c]);
        s16x8 b = *(const s16x8*)(lds + LDS_BUFB + roff[c + 4]);
        c0[c] = __builtin_amdgcn_mfma_f32_16x16x32_bf16(a, w3r[c][0], c0[c], 0, 0, 0);
        c1[c] = __builtin_amdgcn_mfma_f32_16x16x32_bf16(a, w3r[c][1], c1[c], 0, 0, 0);
        c0[c] = __builtin_amdgcn_mfma_f32_16x16x32_bf16(b, w3r[c + 4][0], c0[c], 0, 0, 0);
        c1[c] = __builtin_amdgcn_mfma_f32_16x16x32_bf16(b, w3r[c + 4][1], c1[c], 0, 0, 0);
      }
      __builtin_amdgcn_s_setprio(0);
      acc0 = (c0[0] + c0[1]) + (c0[2] + c0[3]);
      acc1 = (c1[0] + c1[1]) + (c1[2] + c1[3]);
      #pragma unroll
      for (int r = 0; r < 4; ++r) {
        unsigned p;
        float lo = tanh_s(acc0[r]), hi = tanh_s(acc1[r]);
        asm("v_cvt_pk_bf16_f32 %0, %1, %2" : "=v"(p) : "v"(lo), "v"(hi));
        *(unsigned*)(lds + LDS_BUFA + woff[r]) = p;
      }

      // ---- L4 fused (NO barrier): wave wv's K-slice == seg wv it just wrote ----
      asm volatile("s_waitcnt lgkmcnt(0)" ::: "memory");
      __builtin_amdgcn_sched_barrier(0);
      {
        s16x8 a = *(const s16x8*)(lds + LDS_BUFA + roff[0]);   // kt = wv
        f32x4 p4 = __builtin_amdgcn_mfma_f32_16x16x32_bf16(a, w4r, z4, 0, 0, 0);
        #pragma unroll
        for (int r = 0; r < 4; ++r)
          *(float*)(lds + pwoff[r]) = p4[r];
      }
      __syncthreads();

      // ---- reduce + Heun (tid<256: row rs, col cs) ----
      if (tid < 256) {
        const char* pb = lds + LDS_PART + ((rs * 128 + cs * 8) << 2);
        f32x4 va = *(const f32x4*)pb;
        f32x4 vb = *(const f32x4*)(pb + 16);
        f32x4 sv = va + vb;
        float s = ((sv[0] + sv[1]) + (sv[2] + sv[3])) + b4v;
        if (cs < 12) {
          int byt = rs * 64 + ((cs * 4) ^ ((rs & 3) << 4));
          if (ev == 0) {
            zir = zr + DT * s;
            *(ushort_t*)(lds + LDS_AIN + byt) = f2bf(zir);   // MLP#2 input
          } else {
            float yi = yr + DT * s;
            zr = PP * zir + (1.f - PP) * yi;
            yr = PP * yi + (1.f - PP) * zr;
            *(ushort_t*)(lds + LDS_AIN + byt) = f2bf(yr);    // next MLP#1 input
          }
        }
      }
      __syncthreads();
    }
  }

  // ---- output: action_aug = [z | y] ----
  if (tid < 256 && cs < 12) {
    out[(row0 + rs) * XDIM + cs]      = zr;
    out[(row0 + rs) * XDIM + 12 + cs] = yr;
  }
}

extern "C" void kernel_launch(void* const* d_in, const int* in_sizes, int n_in,
                              void* d_out, int out_size, void* d_ws, size_t ws_size,
                              hipStream_t stream) {
  const float* obs = (const float*)d_in[0];
  const float* x0  = (const float*)d_in[1];
  const float* W1  = (const float*)d_in[2];
  const float* b1  = (const float*)d_in[3];
  const float* W2  = (const float*)d_in[4];
  const float* b2  = (const float*)d_in[5];
  const float* W3  = (const float*)d_in[6];
  const float* b3  = (const float*)d_in[7];
  const float* W4  = (const float*)d_in[8];
  const float* b4  = (const float*)d_in[9];
  const int*   jac = (const int*)d_in[10];
  float* out = (float*)d_out;
  ushort_t* ws = (ushort_t*)d_ws;

  prep_kernel<<<FRAG_BLOCKS + LP_BLOCKS, 256, 0, stream>>>(W1, b1, W2, W3, W4, x0, jac, out, ws);
  flow_main<<<128, 512, 0, stream>>>(obs, x0, W1, b2, b3, b4, ws, out);
}